// Round 6
// baseline (310.842 us; speedup 1.0000x reference)
//
#include <hip/hip_runtime.h>

// DIAGNOSTIC ROUND: same upfirdn2d algorithm, grid deliberately reduced
// 2048 -> 512 blocks so the kernel's dispatch duration exceeds the ~165us
// harness poison-fills and finally shows up in the top-5 rocprof rows with
// its own FETCH_SIZE / WRITE_SIZE / VALUBusy / OccupancyPercent. Six
// structural variants have converged at kernel ~140us vs a 53us traffic
// model (910MB effective vs 335MB nominal); the counters decide between
// hidden-traffic vs mixed-stream-inefficiency. Traffic counters are
// structure-independent, so this probe answers for the fast variant too.
//
// STRIP=64 variant: each thread owns input cols 2q..2q+1 of a FULL image
// column (rows 0..63), rolling 3-row horizontal-filtered window. Zero
// vertical halo re-reads (minimum possible read traffic: each input elem
// read exactly once). Stores: nontemporal, fully lane-contiguous f32x4
// (512B per half-wave per instruction), sequential down the image.
// Lanes 32..63 are the next image; the width-64 shfl crossing the lane
// 31/32 seam is pulled only by q==0/q==31 lanes, which are exactly the
// boundary-zero lanes, so the wrong-image value is masked.

typedef float f32x4 __attribute__((ext_vector_type(4)));

__global__ __launch_bounds__(256) void upsample_2x_kernel(
    const float* __restrict__ x, float* __restrict__ out) {
  int idx = blockIdx.x * 256 + threadIdx.x;
  int q   = idx & 31;   // col pair: input cols 2q,2q+1 -> output cols 4q..4q+3
  int img = idx >> 5;   // B*C image (32 threads per image)

  const float* xi = x + (size_t)img * (64 * 64) + 2 * q;
  float*       oi = out + (size_t)img * (128 * 128) + 4 * q;

  // Horizontal pass on one input row -> output cols 4q..4q+3 (pre-vertical).
  auto horiz = [&](float2 v) -> f32x4 {
    float left  = __shfl_up(v.y, 1);    // lane q-1's col 2q-1
    float right = __shfl_down(v.x, 1);  // lane q+1's col 2q+2
    if (q == 0)  left  = 0.f;
    if (q == 31) right = 0.f;
    float a = 0.75f * v.x, b = 0.75f * v.y;
    f32x4 h;
    h[0] = a + 0.25f * left;   // col 4q   (even)
    h[1] = a + 0.25f * v.y;    // col 4q+1 (odd)
    h[2] = b + 0.25f * v.x;    // col 4q+2 (even)
    h[3] = b + 0.25f * right;  // col 4q+3 (odd)
    return h;
  };

  f32x4 Hm1 = horiz(make_float2(0.f, 0.f));      // H[-1] = zero row
  f32x4 H0  = horiz(*(const float2*)(xi));       // H[0]
  float* op = oi;

#pragma unroll 8
  for (int r = 0; r < 64; ++r) {
    f32x4 H1 = (r < 63) ? horiz(*(const float2*)(xi + (r + 1) * 64))
                        : horiz(make_float2(0.f, 0.f));
    f32x4 c  = 0.75f * H0;             // shared center term
    f32x4 o0 = c + 0.25f * Hm1;        // out[2r]   = 0.25*H[r-1] + 0.75*H[r]
    f32x4 o1 = c + 0.25f * H1;         // out[2r+1] = 0.75*H[r] + 0.25*H[r+1]
    __builtin_nontemporal_store(o0, (f32x4*)(op));
    __builtin_nontemporal_store(o1, (f32x4*)(op + 128));
    op += 256;
    Hm1 = H0;
    H0  = H1;
  }
}

extern "C" void kernel_launch(void* const* d_in, const int* in_sizes, int n_in,
                              void* d_out, int out_size, void* d_ws, size_t ws_size,
                              hipStream_t stream) {
  const float* x = (const float*)d_in[0];
  float* out = (float*)d_out;
  // 16*256 images * 32 col-pairs = 131,072 threads -> 512 blocks (2/CU):
  // deliberately under-occupied so the kernel dispatch outlasts the 165us
  // poison fills and becomes visible in the top-5 counter rows.
  const int blocks = (16 * 256 * 32) / 256;  // 512
  upsample_2x_kernel<<<blocks, 256, 0, stream>>>(x, out);
}